// Round 14
// baseline (204.179 us; speedup 1.0000x reference)
//
#include <hip/hip_runtime.h>
#include <stdint.h>
#include <stddef.h>

typedef unsigned short u16;
typedef __attribute__((ext_vector_type(4))) unsigned short u16x4;
typedef __attribute__((ext_vector_type(8))) short bf16x8;
typedef __attribute__((ext_vector_type(4))) float f32x4;
typedef __attribute__((ext_vector_type(16))) float f32x16;

// problem dims (fixed by setup_inputs)
#define B_   2
#define T_   2048
#define NH   16
#define NKV  8
#define HD   128

// (1/sqrt(128)) * log2(e) — folded into Q during rms_rope; softmax runs base-2
#define QSCALE 0.1275174457f

__device__ __forceinline__ u16 f2bf(float f) {
  union { float f; uint32_t u; } v; v.f = f;
  uint32_t u = v.u;
  u += 0x7FFFu + ((u >> 16) & 1u);   // round-to-nearest-even
  return (u16)(u >> 16);
}
__device__ __forceinline__ float bf2f(u16 h) {
  union { uint32_t u; float f; } v; v.u = ((uint32_t)h) << 16;
  return v.f;
}
__device__ __forceinline__ uint32_t cvt_pk_bf16(float lo, float hi) {
  uint32_t r;
  asm("v_cvt_pk_bf16_f32 %0, %1, %2" : "=v"(r) : "v"(lo), "v"(hi));
  return r;
}
__device__ __forceinline__ float fexp2(float x) {   // 2^x, single v_exp_f32
  float r;
  asm("v_exp_f32 %0, %1" : "=v"(r) : "v"(x));
  return r;
}

// async global->LDS, 16B per lane. LDS dest must be linear in lane order.
__device__ __forceinline__ void gload_lds16(const void* g, void* l) {
  __builtin_amdgcn_global_load_lds(
      (__attribute__((address_space(1))) void*)g,
      (__attribute__((address_space(3))) void*)l, 16, 0, 0);
}

#define WAITVM(N) do { asm volatile("s_waitcnt vmcnt(" #N ")" ::: "memory"); } while (0)

// ---------------- fused fp32 -> bf16 conversion (all 5 tensors, 1 launch) ---
__global__ __launch_bounds__(256) void cvt_all(const float* __restrict__ x,
                                               const float* __restrict__ Wq,
                                               const float* __restrict__ Wk,
                                               const float* __restrict__ Wv,
                                               const float* __restrict__ Wo,
                                               u16* __restrict__ ws0) {
  const int blk = blockIdx.x;
  const float* src; u16* dst; int lb;
  if (blk < 8192)       { src = x;  dst = ws0;              lb = blk; }
  else if (blk < 12288) { src = Wq; dst = ws0 +  8388608;   lb = blk - 8192; }
  else if (blk < 14336) { src = Wk; dst = ws0 + 12582912;   lb = blk - 12288; }
  else if (blk < 16384) { src = Wv; dst = ws0 + 14680064;   lb = blk - 14336; }
  else                  { src = Wo; dst = ws0 + 16777216;   lb = blk - 16384; }
  const int i = lb * 256 + threadIdx.x;
  float4 v = reinterpret_cast<const float4*>(src)[i];
  u16x4 o;
  o.x = f2bf(v.x); o.y = f2bf(v.y); o.z = f2bf(v.z); o.w = f2bf(v.w);
  reinterpret_cast<u16x4*>(dst)[i] = o;
}

// ---------------- GEMM v4: 4-region rotating pipeline, BK=32, counted vmcnt -
// C = A[M,K]*B[N,K]^T. 512 threads = 8 waves (2M x 4N). Grid must be 256.
// Regions (t&3) hold tiles t..t+3 simultaneously; per-tile body:
//   waitcnt vmcnt(2*LPT)  -> own tile-t loads landed (counted, never 0)
//   s_barrier (raw)       -> collectively resident; frees region (t-1)&3
//   stage(t+3)            -> writes region (t-1)&3 (no live readers)
//   ds_read + MFMA        -> region t&3
// Ledger: reads of region r only in body r(t); writes to region r only in body
// t = r-3 (mod 4), after barrier(t) which all waves passed having consumed
// body t-1 (lgkmcnt'd before their MFMAs). BK=32 rows (64B) hit all 8 LDS
// slots uniformly -> conflict-free without swizzle.
template<int BM, int BN, int STORE>
__global__ __launch_bounds__(512, 2) void gemm4(const u16* __restrict__ A,
                                                const u16* __restrict__ Bm,
                                                void* __restrict__ C0,
                                                void* __restrict__ C1,
                                                void* __restrict__ C2,
                                                int M, int N, int K) {
  constexpr int FM  = BM / 32;
  constexpr int FN  = BN / 64;
  constexpr int RSZ = (BM + BN) * 32;        // u16 per region
  constexpr int LPT = BM / 128 + BN / 128;   // gloads per thread per tile
  __shared__ u16 lds[4 * RSZ];

  const int tid  = threadIdx.x;
  const int lane = tid & 63;
  const int wid  = tid >> 6;
  const int lr   = lane & 15;
  const int lg   = lane >> 4;
  const int wm0 = (wid >> 2) * (BM / 2);
  const int wn0 = (wid & 3) * (BN / 4);

  const int s  = ((blockIdx.x & 7) << 5) | (blockIdx.x >> 3);
  const int nx = N / BN;
  const int m0 = (s / nx) * BM;
  const int n0 = (s % nx) * BN;

  f32x4 acc[FM][FN];
#pragma unroll
  for (int i = 0; i < FM; ++i)
#pragma unroll
    for (int j = 0; j < FN; ++j) acc[i][j] = (f32x4){0.f, 0.f, 0.f, 0.f};

  auto stage = [&](int kt) {
    u16* Ab = lds + (size_t)(kt & 3) * RSZ;
    u16* Bb = Ab + BM * 32;
    const int k0 = kt << 5;
#pragma unroll
    for (int it = 0; it < BM / 128; ++it) {    // 4 chunks per 64B row
      const int CI = it * 512 + tid;
      const int row = CI >> 2, c = CI & 3;
      gload_lds16(A + (size_t)(m0 + row) * K + k0 + c * 8,
                  (char*)Ab + (size_t)CI * 16);
    }
#pragma unroll
    for (int it = 0; it < BN / 128; ++it) {
      const int CI = it * 512 + tid;
      const int row = CI >> 2, c = CI & 3;
      gload_lds16(Bm + (size_t)(n0 + row) * K + k0 + c * 8,
                  (char*)Bb + (size_t)CI * 16);
    }
  };

  const int nk = K >> 5;
  stage(0); stage(1); stage(2);
  for (int t = 0; t < nk; ++t) {
    const int ahead = (nk - 1 - t) < 2 ? (nk - 1 - t) : 2;  // unconfirmed tiles beyond t
    if constexpr (LPT == 4) {
      if (ahead == 2) WAITVM(8);
      else if (ahead == 1) WAITVM(4);
      else WAITVM(0);
    } else {   // LPT == 3
      if (ahead == 2) WAITVM(6);
      else if (ahead == 1) WAITVM(3);
      else WAITVM(0);
    }
    __builtin_amdgcn_sched_barrier(0);
    __builtin_amdgcn_s_barrier();
    __builtin_amdgcn_sched_barrier(0);
    if (t + 3 < nk) stage(t + 3);

    const u16* Ab = lds + (size_t)(t & 3) * RSZ;
    const u16* Bb = Ab + BM * 32;
    bf16x8 af[FM], bfr[FN];
#pragma unroll
    for (int mt = 0; mt < FM; ++mt)
      af[mt] = *reinterpret_cast<const bf16x8*>(
          (const char*)Ab + (wm0 + mt * 16 + lr) * 64 + lg * 16);
#pragma unroll
    for (int nt = 0; nt < FN; ++nt)
      bfr[nt] = *reinterpret_cast<const bf16x8*>(
          (const char*)Bb + (wn0 + nt * 16 + lr) * 64 + lg * 16);
    __builtin_amdgcn_s_setprio(1);
#pragma unroll
    for (int mt = 0; mt < FM; ++mt)
#pragma unroll
      for (int nt = 0; nt < FN; ++nt)
        acc[mt][nt] = __builtin_amdgcn_mfma_f32_16x16x32_bf16(
            af[mt], bfr[nt], acc[mt][nt], 0, 0, 0);
    __builtin_amdgcn_s_setprio(0);
  }

  if (STORE == 3) {
    u16* Qd = (u16*)C0; u16* Kd = (u16*)C1; u16* Vd = (u16*)C2;
    if (n0 < 2048) {
#pragma unroll
      for (int mt = 0; mt < FM; ++mt) {
        const int row = m0 + wm0 + mt * 16 + lg * 4;
#pragma unroll
        for (int nt = 0; nt < FN; ++nt) {
          const int col = n0 + wn0 + nt * 16 + lr;
#pragma unroll
          for (int r = 0; r < 4; ++r)
            Qd[(size_t)(row + r) * 2048 + col] = f2bf(acc[mt][nt][r]);
        }
      }
    } else if (n0 < 3072) {
#pragma unroll
      for (int mt = 0; mt < FM; ++mt) {
        const int row = m0 + wm0 + mt * 16 + lg * 4;
#pragma unroll
        for (int nt = 0; nt < FN; ++nt) {
          const int col = n0 + wn0 + nt * 16 + lr - 2048;
#pragma unroll
          for (int r = 0; r < 4; ++r)
            Kd[(size_t)(row + r) * 1024 + col] = f2bf(acc[mt][nt][r]);
        }
      }
    } else {   // V^T: Vd[(b*1024 + vc)*T_ + t]
#pragma unroll
      for (int mt = 0; mt < FM; ++mt) {
        const int row = m0 + wm0 + mt * 16 + lg * 4;
        const int b = row >> 11;
        const int t = row & (T_ - 1);
#pragma unroll
        for (int nt = 0; nt < FN; ++nt) {
          const int vc = n0 + wn0 + nt * 16 + lr - 3072;
          u16x4 v;
          v.x = f2bf(acc[mt][nt][0]); v.y = f2bf(acc[mt][nt][1]);
          v.z = f2bf(acc[mt][nt][2]); v.w = f2bf(acc[mt][nt][3]);
          *reinterpret_cast<u16x4*>(Vd + ((size_t)(b * 1024 + vc)) * T_ + t) = v;
        }
      }
    }
  } else {     // STORE == 2: f32 row-major
    float* C = (float*)C0;
#pragma unroll
    for (int mt = 0; mt < FM; ++mt) {
      const int row = m0 + wm0 + mt * 16 + lg * 4;
#pragma unroll
      for (int nt = 0; nt < FN; ++nt) {
        const int col = n0 + wn0 + nt * 16 + lr;
#pragma unroll
        for (int r = 0; r < 4; ++r)
          C[(size_t)(row + r) * N + col] = acc[mt][nt][r];
      }
    }
  }
}

// ---------------- per-head RMSNorm + RoPE on Q and K (in-place, bf16) -------
__global__ __launch_bounds__(256) void rms_rope(u16* __restrict__ Q, u16* __restrict__ Kb,
                                                const float* __restrict__ cosT,
                                                const float* __restrict__ sinT,
                                                const int* __restrict__ pos,
                                                const float* __restrict__ qw,
                                                const float* __restrict__ kw) {
  const int wave = blockIdx.x * 4 + (threadIdx.x >> 6);
  const int lane = threadIdx.x & 63;
  const int bt = wave & (B_ * T_ - 1);
  const int hh = wave >> 12;
  u16* ptr;
  const float* w;
  float post;
  if (hh < NH) { ptr = Q + (size_t)bt * (NH * HD) + hh * HD; w = qw; post = QSCALE; }
  else         { ptr = Kb + (size_t)bt * (NKV * HD) + (hh - NH) * HD; w = kw; post = 1.0f; }
  const int p = pos[bt];

  float e0 = bf2f(ptr[lane]);
  float e1 = bf2f(ptr[lane + 64]);
  float ss = e0 * e0 + e1 * e1;
#pragma unroll
  for (int off = 1; off < 64; off <<= 1) ss += __shfl_xor(ss, off, 64);
  const float r = rsqrtf(ss * (1.0f / 128.0f) + 1e-6f) * post;
  const float n0 = e0 * r * w[lane];
  const float n1 = e1 * r * w[lane + 64];
  const float c0 = cosT[(size_t)p * HD + lane], c1 = cosT[(size_t)p * HD + lane + 64];
  const float s0 = sinT[(size_t)p * HD + lane], s1 = sinT[(size_t)p * HD + lane + 64];
  ptr[lane]      = f2bf(n0 * c0 - n1 * s0);
  ptr[lane + 64] = f2bf(n1 * c1 + n0 * s1);
}

// ---------------- causal flash attention (round-8 proven, byte-identical) ---
__global__ __launch_bounds__(256, 2) void flash_attn5(const u16* __restrict__ Qw,
                                                      const u16* __restrict__ Kw,
                                                      const u16* __restrict__ VTw,
                                                      u16* __restrict__ Ow) {
  __shared__ __align__(16) char smem[65536];

  const int tid  = threadIdx.x;
  const int lane = tid & 63;
  const int wid  = tid >> 6;
  const int rl   = lane & 31;
  const int hi   = lane >> 5;
  const int blk  = blockIdx.x;
  const int qtr = blk >> 5;
  const int qt  = (blk < 256) ? (15 - qtr) : (qtr - 8);
  const int bh  = blk & 31;
  const int b   = bh >> 4, h = bh & 15, kvh = h >> 1;
  const int q0w = qt * 128 + wid * 32;
  const int qg  = q0w + rl;
  const int kswz = (rl & 15) << 4;

  bf16x8 qf[8];
  {
    const u16* qp = Qw + ((size_t)(b * T_) + qg) * (NH * HD) + h * HD + hi * 8;
#pragma unroll
    for (int kd = 0; kd < 8; ++kd) qf[kd] = *reinterpret_cast<const bf16x8*>(qp + kd * 16);
  }

  f32x16 ot[4];
#pragma unroll
  for (int dt = 0; dt < 4; ++dt)
#pragma unroll
    for (int r = 0; r < 16; ++r) ot[dt][r] = 0.f;
  float m = -1e30f, lsum = 0.f;

  auto stageKV = [&](int kt, int p) {
    char* Kb = smem + p * 32768;
    char* Vb = Kb + 16384;
    {
      const int row = tid >> 4, ch = tid & 15;
#pragma unroll
      for (int it = 0; it < 4; ++it) {
        const int rr = it * 16 + row;
        const int scol = ((ch * 16) ^ ((rr & 15) << 4)) >> 1;
        gload_lds16(Kw + ((size_t)(b * T_) + kt * 64 + rr) * (NKV * HD) + kvh * HD + scol,
                    Kb + (it * 256 + tid) * 16);
      }
    }
    {
      const int row = tid >> 3, ch = tid & 7;
#pragma unroll
      for (int it = 0; it < 4; ++it) {
        const int rr = it * 32 + row;
        const int scol = ((ch * 16) ^ ((rr & 7) << 4)) >> 1;
        gload_lds16(VTw + ((size_t)((b * NKV + kvh) * HD) + rr) * T_ + kt * 64 + scol,
                    Vb + (it * 256 + tid) * 16);
      }
    }
  };

  const int nkt = 2 * qt + 2;
  stageKV(0, 0);
  __syncthreads();
  for (int kt = 0; kt < nkt; ++kt) {
    const int cur = kt & 1;
    if (kt + 1 < nkt) stageKV(kt + 1, cur ^ 1);

    if (64 * kt <= q0w + 31) {
      const u16* Kb = (const u16*)(smem + cur * 32768);
      const u16* Vb = (const u16*)(smem + cur * 32768 + 16384);

      f32x16 s0, s1;
#pragma unroll
      for (int r = 0; r < 16; ++r) { s0[r] = 0.f; s1[r] = 0.f; }
      __builtin_amdgcn_s_setprio(1);
#pragma unroll
      for (int kd = 0; kd < 8; ++kd) {
        const int cb = (kd * 32 + hi * 16) ^ kswz;
        const bf16x8 k0 = *reinterpret_cast<const bf16x8*>((const char*)Kb + rl * 256 + cb);
        const bf16x8 k1 = *reinterpret_cast<const bf16x8*>((const char*)Kb + (32 + rl) * 256 + cb);
        s0 = __builtin_amdgcn_mfma_f32_32x32x16_bf16(k0, qf[kd], s0, 0, 0, 0);
        s1 = __builtin_amdgcn_mfma_f32_32x32x16_bf16(k1, qf[kd], s1, 0, 0, 0);
      }
      __builtin_amdgcn_s_setprio(0);

      const int kv0 = kt * 64;
      const bool maskT = (kv0 + 63 > q0w);
      float rm = -1e30f;
      if (maskT) {
#pragma unroll
        for (int r = 0; r < 16; ++r) {
          const int cr = (r & 3) + 8 * (r >> 2) + 4 * hi;
          float a = s0[r], c = s1[r];
          if (kv0 + cr > qg)      a = -1e30f;
          if (kv0 + 32 + cr > qg) c = -1e30f;
          s0[r] = a; s1[r] = c;
          rm = fmaxf(rm, fmaxf(a, c));
        }
      } else {
#pragma unroll
        for (int r = 0; r < 16; ++r) rm = fmaxf(rm, fmaxf(s0[r], s1[r]));
      }
      rm = fmaxf(rm, __shfl_xor(rm, 32));

      if (!__all(rm <= m + 8.0f)) {
        const float mn = fmaxf(m, rm);
        const float al = fexp2(m - mn);
        lsum *= al;
#pragma unroll
        for (int dt = 0; dt < 4; ++dt)
#pragma unroll
          for (int r = 0; r < 16; ++r) ot[dt][r] *= al;
        m = mn;
      }
      float rs = 0.f;
#pragma unroll
      for (int r = 0; r < 16; ++r) {
        const float p0 = fexp2(s0[r] - m);
        const float p1 = fexp2(s1[r] - m);
        s0[r] = p0; s1[r] = p1;
        rs += p0 + p1;
      }
      rs += __shfl_xor(rs, 32);
      lsum += rs;

      bf16x8 pf[2][2];
#pragma unroll
      for (int ks = 0; ks < 2; ++ks) {
        {
          uint32_t X0 = cvt_pk_bf16(s0[8 * ks + 0], s0[8 * ks + 1]);
          uint32_t X1 = cvt_pk_bf16(s0[8 * ks + 2], s0[8 * ks + 3]);
          uint32_t Y0 = cvt_pk_bf16(s0[8 * ks + 4], s0[8 * ks + 5]);
          uint32_t Y1 = cvt_pk_bf16(s0[8 * ks + 6], s0[8 * ks + 7]);
          asm volatile("v_permlane32_swap_b32 %0, %1" : "+v"(X0), "+v"(Y0));
          asm volatile("v_permlane32_swap_b32 %0, %1" : "+v"(X1), "+v"(Y1));
          union { uint32_t w[4]; bf16x8 v; } u;
          u.w[0] = X0; u.w[1] = X1; u.w[2] = Y0; u.w[3] = Y1;
          pf[0][ks] = u.v;
        }
        {
          uint32_t X0 = cvt_pk_bf16(s1[8 * ks + 0], s1[8 * ks + 1]);
          uint32_t X1 = cvt_pk_bf16(s1[8 * ks + 2], s1[8 * ks + 3]);
          uint32_t Y0 = cvt_pk_bf16(s1[8 * ks + 4], s1[8 * ks + 5]);
          uint32_t Y1 = cvt_pk_bf16(s1[8 * ks + 6], s1[8 * ks + 7]);
          asm volatile("v_permlane32_swap_b32 %0, %1" : "+v"(X0), "+v"(Y0));
          asm volatile("v_permlane32_swap_b32 %0, %1" : "+v"(X1), "+v"(Y1));
          union { uint32_t w[4]; bf16x8 v; } u;
          u.w[0] = X0; u.w[1] = X1; u.w[2] = Y0; u.w[3] = Y1;
          pf[1][ks] = u.v;
        }
      }

      __builtin_amdgcn_s_setprio(1);
#pragma unroll
      for (int dt = 0; dt < 4; ++dt) {
        const int rv = dt * 32 + rl;
#pragma unroll
        for (int kvc = 0; kvc < 2; ++kvc)
#pragma unroll
          for (int ks = 0; ks < 2; ++ks) {
            const int cb = (kvc * 64 + ks * 32 + hi * 16) ^ ((rv & 7) << 4);
            const bf16x8 vf = *reinterpret_cast<const bf16x8*>((const char*)Vb + rv * 128 + cb);
            ot[dt] = __builtin_amdgcn_mfma_f32_32x32x16_bf16(vf, pf[kvc][ks], ot[dt], 0, 0, 0);
          }
      }
      __builtin_amdgcn_s_setprio(0);
    }
    __syncthreads();
  }

  const float inv = 1.0f / lsum;
  u16* ep = (u16*)smem + wid * (32 * 136);
#pragma unroll
  for (int dt = 0; dt < 4; ++dt)
#pragma unroll
    for (int r = 0; r < 16; ++r) {
      const int d = dt * 32 + (r & 3) + 8 * (r >> 2) + 4 * hi;
      ep[rl * 136 + d] = f2bf(ot[dt][r] * inv);
    }
  const int dh = hi * 64;
  const u16* srcp = (u16*)smem + wid * (32 * 136) + rl * 136 + dh;
  u16* gdst = Ow + ((size_t)(b * T_) + q0w + rl) * (NH * HD) + h * HD + dh;
#pragma unroll
  for (int c2 = 0; c2 < 8; ++c2)
    *reinterpret_cast<bf16x8*>(gdst + c2 * 8) =
        *reinterpret_cast<const bf16x8*>(srcp + c2 * 8);
}

// ---------------- host launch ----------------
extern "C" void kernel_launch(void* const* d_in, const int* in_sizes, int n_in,
                              void* d_out, int out_size, void* d_ws, size_t ws_size,
                              hipStream_t stream) {
  (void)in_sizes; (void)n_in; (void)out_size; (void)ws_size;
  const float* x    = (const float*)d_in[0];
  const float* cosT = (const float*)d_in[1];
  const float* sinT = (const float*)d_in[2];
  const int*   pos  = (const int*)d_in[3];
  const float* Wq   = (const float*)d_in[4];
  const float* Wk   = (const float*)d_in[5];
  const float* Wv   = (const float*)d_in[6];
  const float* Wo   = (const float*)d_in[7];
  const float* qw   = (const float*)d_in[8];
  const float* kw   = (const float*)d_in[9];
  float* out = (float*)d_out;

  // workspace map (bytes). Wqb/Wkb/Wvb contiguous -> one [4096][2048] weight.
  char* ws = (char*)d_ws;
  u16* xb   = (u16*)(ws + 0);          // [4096][2048]
  u16* Wqb  = (u16*)(ws + 16777216);   // [2048][2048] (QKV part 1)
  u16* Wob  = (u16*)(ws + 33554432);   // [2048][2048]
  u16* Qws  = (u16*)(ws + 41943040);   // [4096][2048]
  u16* Kws  = (u16*)(ws + 58720256);   // [4096][1024]
  u16* VTws = (u16*)(ws + 67108864);   // [2][1024][2048]
  u16* Aws  = (u16*)(ws + 75497472);   // [4096][2048]

  cvt_all<<<20480, 256, 0, stream>>>(x, Wq, Wk, Wv, Wo, (u16*)ws);

  // fused QKV projection: 256x256 tile, 4-region BK=32 pipeline, 256 blocks
  gemm4<256, 256, 3><<<256, 512, 0, stream>>>(xb, Wqb, Qws, Kws, VTws,
                                              4096, 4096, 2048);

  rms_rope<<<24576, 256, 0, stream>>>(Qws, Kws, cosT, sinT, pos, qw, kw);

  flash_attn5<<<512, 256, 0, stream>>>(Qws, Kws, VTws, Aws);

  // output projection: 128x256 tile, same pipeline, 256 blocks
  gemm4<128, 256, 2><<<256, 512, 0, stream>>>(Aws, Wob, out, nullptr, nullptr,
                                              4096, 2048, 2048);
}

// Round 15
// 191.025 us; speedup vs baseline: 1.0689x; 1.0689x over previous
//
#include <hip/hip_runtime.h>
#include <stdint.h>
#include <stddef.h>

typedef unsigned short u16;
typedef __attribute__((ext_vector_type(4))) unsigned short u16x4;
typedef __attribute__((ext_vector_type(8))) short bf16x8;
typedef __attribute__((ext_vector_type(4))) float f32x4;
typedef __attribute__((ext_vector_type(16))) float f32x16;

// problem dims (fixed by setup_inputs)
#define B_   2
#define T_   2048
#define NH   16
#define NKV  8
#define HD   128

// (1/sqrt(128)) * log2(e) — folded into Q during rms_rope; softmax runs base-2
#define QSCALE 0.1275174457f

__device__ __forceinline__ u16 f2bf(float f) {
  union { float f; uint32_t u; } v; v.f = f;
  uint32_t u = v.u;
  u += 0x7FFFu + ((u >> 16) & 1u);   // round-to-nearest-even
  return (u16)(u >> 16);
}
__device__ __forceinline__ float bf2f(u16 h) {
  union { uint32_t u; float f; } v; v.u = ((uint32_t)h) << 16;
  return v.f;
}
__device__ __forceinline__ uint32_t cvt_pk_bf16(float lo, float hi) {
  uint32_t r;
  asm("v_cvt_pk_bf16_f32 %0, %1, %2" : "=v"(r) : "v"(lo), "v"(hi));
  return r;
}
__device__ __forceinline__ float fexp2(float x) {   // 2^x, single v_exp_f32
  float r;
  asm("v_exp_f32 %0, %1" : "=v"(r) : "v"(x));
  return r;
}

// async global->LDS, 16B per lane. LDS dest must be linear in lane order.
__device__ __forceinline__ void gload_lds16(const void* g, void* l) {
  __builtin_amdgcn_global_load_lds(
      (__attribute__((address_space(1))) void*)g,
      (__attribute__((address_space(3))) void*)l, 16, 0, 0);
}

// ---------------- fused fp32 -> bf16 conversion (all 5 tensors, 1 launch) ---
__global__ __launch_bounds__(256) void cvt_all(const float* __restrict__ x,
                                               const float* __restrict__ Wq,
                                               const float* __restrict__ Wk,
                                               const float* __restrict__ Wv,
                                               const float* __restrict__ Wo,
                                               u16* __restrict__ ws0) {
  const int blk = blockIdx.x;
  const float* src; u16* dst; int lb;
  if (blk < 8192)       { src = x;  dst = ws0;              lb = blk; }
  else if (blk < 12288) { src = Wq; dst = ws0 +  8388608;   lb = blk - 8192; }
  else if (blk < 14336) { src = Wk; dst = ws0 + 12582912;   lb = blk - 12288; }
  else if (blk < 16384) { src = Wv; dst = ws0 + 14680064;   lb = blk - 14336; }
  else                  { src = Wo; dst = ws0 + 16777216;   lb = blk - 16384; }
  const int i = lb * 256 + threadIdx.x;
  float4 v = reinterpret_cast<const float4*>(src)[i];
  u16x4 o;
  o.x = f2bf(v.x); o.y = f2bf(v.y); o.z = f2bf(v.z); o.w = f2bf(v.w);
  reinterpret_cast<u16x4*>(dst)[i] = o;
}

// ---------------- GEMM v2: C = A[M,K]*B[N,K]^T, 2-phase dbuf + T2 swizzle ----
// 512 threads = 8 waves (2M x 4N). BK=64. Grid must be exactly 256 blocks.
// NOTE: 256^2 tile w/ 8 waves is structurally 1 block/CU (acc=128 VGPR);
// do NOT force higher occupancy via launch_bounds — it spills (round 10).
// Runs at ~50% of its MFMA-cycle floor: the 2-barrier-per-K-tile drain is the
// structural ceiling (m97-class); schedule grafts regressed (rounds 9/10/14).
template<int BM, int BN, int STORE>
__global__ __launch_bounds__(512, 2) void gemm2(const u16* __restrict__ A,
                                                const u16* __restrict__ Bm,
                                                void* __restrict__ C0,
                                                void* __restrict__ C1,
                                                void* __restrict__ C2,
                                                int M, int N, int K) {
  constexpr int FM  = BM / 32;
  constexpr int FN  = BN / 64;
  constexpr int ASZ = BM * 64;
  constexpr int BSZ = BN * 64;
  __shared__ u16 lds[2 * (ASZ + BSZ)];

  const int tid  = threadIdx.x;
  const int lane = tid & 63;
  const int wid  = tid >> 6;
  const int lr   = lane & 15;
  const int lg   = lane >> 4;
  const int wm0 = (wid >> 2) * (BM / 2);
  const int wn0 = (wid & 3) * (BN / 4);

  const int s  = ((blockIdx.x & 7) << 5) | (blockIdx.x >> 3);
  const int nx = N / BN;
  const int m0 = (s / nx) * BM;
  const int n0 = (s % nx) * BN;

  f32x4 acc[FM][FN];
#pragma unroll
  for (int i = 0; i < FM; ++i)
#pragma unroll
    for (int j = 0; j < FN; ++j) acc[i][j] = (f32x4){0.f, 0.f, 0.f, 0.f};

  auto stage = [&](int kt, int p) {
    const int k0 = kt << 6;
    u16* Ab = lds + p * (ASZ + BSZ);
    u16* Bb = Ab + ASZ;
#pragma unroll
    for (int it = 0; it < BM / 64; ++it) {
      const int CI = it * 512 + tid;
      const int row = CI >> 3, c = CI & 7;
      gload_lds16(A + (size_t)(m0 + row) * K + k0 + ((c ^ (row & 7)) << 3),
                  (char*)Ab + (size_t)CI * 16);
    }
#pragma unroll
    for (int it = 0; it < BN / 64; ++it) {
      const int CI = it * 512 + tid;
      const int row = CI >> 3, c = CI & 7;
      gload_lds16(Bm + (size_t)(n0 + row) * K + k0 + ((c ^ (row & 7)) << 3),
                  (char*)Bb + (size_t)CI * 16);
    }
  };

  const int nk = K >> 6;
  stage(0, 0);
  __syncthreads();
  int cur = 0;
  for (int kt = 0; kt < nk; ++kt) {
    if (kt + 1 < nk) stage(kt + 1, cur ^ 1);
    const u16* Ab = lds + cur * (ASZ + BSZ);
    const u16* Bb = Ab + ASZ;
#pragma unroll
    for (int kk = 0; kk < 2; ++kk) {
      bf16x8 af[FM], bfr[FN];
#pragma unroll
      for (int mt = 0; mt < FM; ++mt) {
        const int ar = wm0 + mt * 16 + lr;
        af[mt] = *reinterpret_cast<const bf16x8*>(
            (const char*)Ab + ar * 128 + ((kk * 64 + lg * 16) ^ ((ar & 7) << 4)));
      }
#pragma unroll
      for (int nt = 0; nt < FN; ++nt) {
        const int br = wn0 + nt * 16 + lr;
        bfr[nt] = *reinterpret_cast<const bf16x8*>(
            (const char*)Bb + br * 128 + ((kk * 64 + lg * 16) ^ ((br & 7) << 4)));
      }
      __builtin_amdgcn_s_setprio(1);
#pragma unroll
      for (int mt = 0; mt < FM; ++mt)
#pragma unroll
        for (int nt = 0; nt < FN; ++nt)
          acc[mt][nt] = __builtin_amdgcn_mfma_f32_16x16x32_bf16(
              af[mt], bfr[nt], acc[mt][nt], 0, 0, 0);
      __builtin_amdgcn_s_setprio(0);
    }
    __syncthreads();
    cur ^= 1;
  }

  if (STORE == 3) {
    u16* Qd = (u16*)C0; u16* Kd = (u16*)C1; u16* Vd = (u16*)C2;
    if (n0 < 2048) {
#pragma unroll
      for (int mt = 0; mt < FM; ++mt) {
        const int row = m0 + wm0 + mt * 16 + lg * 4;
#pragma unroll
        for (int nt = 0; nt < FN; ++nt) {
          const int col = n0 + wn0 + nt * 16 + lr;
#pragma unroll
          for (int r = 0; r < 4; ++r)
            Qd[(size_t)(row + r) * 2048 + col] = f2bf(acc[mt][nt][r]);
        }
      }
    } else if (n0 < 3072) {
#pragma unroll
      for (int mt = 0; mt < FM; ++mt) {
        const int row = m0 + wm0 + mt * 16 + lg * 4;
#pragma unroll
        for (int nt = 0; nt < FN; ++nt) {
          const int col = n0 + wn0 + nt * 16 + lr - 2048;
#pragma unroll
          for (int r = 0; r < 4; ++r)
            Kd[(size_t)(row + r) * 1024 + col] = f2bf(acc[mt][nt][r]);
        }
      }
    } else {   // V^T: Vd[(b*1024 + vc)*T_ + t]
#pragma unroll
      for (int mt = 0; mt < FM; ++mt) {
        const int row = m0 + wm0 + mt * 16 + lg * 4;
        const int b = row >> 11;
        const int t = row & (T_ - 1);
#pragma unroll
        for (int nt = 0; nt < FN; ++nt) {
          const int vc = n0 + wn0 + nt * 16 + lr - 3072;
          u16x4 v;
          v.x = f2bf(acc[mt][nt][0]); v.y = f2bf(acc[mt][nt][1]);
          v.z = f2bf(acc[mt][nt][2]); v.w = f2bf(acc[mt][nt][3]);
          *reinterpret_cast<u16x4*>(Vd + ((size_t)(b * 1024 + vc)) * T_ + t) = v;
        }
      }
    }
  } else {     // STORE == 2: f32 row-major
    float* C = (float*)C0;
#pragma unroll
    for (int mt = 0; mt < FM; ++mt) {
      const int row = m0 + wm0 + mt * 16 + lg * 4;
#pragma unroll
      for (int nt = 0; nt < FN; ++nt) {
        const int col = n0 + wn0 + nt * 16 + lr;
#pragma unroll
        for (int r = 0; r < 4; ++r)
          C[(size_t)(row + r) * N + col] = acc[mt][nt][r];
      }
    }
  }
}

// ---------------- per-head RMSNorm + RoPE on Q and K (in-place, bf16) -------
// Q heads additionally scaled by QSCALE (attn scale * log2e folded; RoPE is
// linear in q so the scale commutes).
__global__ __launch_bounds__(256) void rms_rope(u16* __restrict__ Q, u16* __restrict__ Kb,
                                                const float* __restrict__ cosT,
                                                const float* __restrict__ sinT,
                                                const int* __restrict__ pos,
                                                const float* __restrict__ qw,
                                                const float* __restrict__ kw) {
  const int wave = blockIdx.x * 4 + (threadIdx.x >> 6);
  const int lane = threadIdx.x & 63;
  const int bt = wave & (B_ * T_ - 1);
  const int hh = wave >> 12;
  u16* ptr;
  const float* w;
  float post;
  if (hh < NH) { ptr = Q + (size_t)bt * (NH * HD) + hh * HD; w = qw; post = QSCALE; }
  else         { ptr = Kb + (size_t)bt * (NKV * HD) + (hh - NH) * HD; w = kw; post = 1.0f; }
  const int p = pos[bt];

  float e0 = bf2f(ptr[lane]);
  float e1 = bf2f(ptr[lane + 64]);
  float ss = e0 * e0 + e1 * e1;
#pragma unroll
  for (int off = 1; off < 64; off <<= 1) ss += __shfl_xor(ss, off, 64);
  const float r = rsqrtf(ss * (1.0f / 128.0f) + 1e-6f) * post;
  const float n0 = e0 * r * w[lane];
  const float n1 = e1 * r * w[lane + 64];
  const float c0 = cosT[(size_t)p * HD + lane], c1 = cosT[(size_t)p * HD + lane + 64];
  const float s0 = sinT[(size_t)p * HD + lane], s1 = sinT[(size_t)p * HD + lane + 64];
  ptr[lane]      = f2bf(n0 * c0 - n1 * s0);
  ptr[lane + 64] = f2bf(n1 * c1 + n0 * s1);
}

// ---------------- causal flash attention, swapped-QK^T 32x32, K/V dbuf ------
// 4 waves x 32 q-rows = 128 q/block; KVBLK=64; grid 512 blocks.
// K LDS: [64 rows][256B], 16-slot XOR swizzle (2-way, free).
// V LDS: [128 d][128B], 8-slot XOR swizzle.
// Softmax base-2 (scale*log2e folded into Q), single-path defer-max THR=8.
__global__ __launch_bounds__(256, 2) void flash_attn5(const u16* __restrict__ Qw,
                                                      const u16* __restrict__ Kw,
                                                      const u16* __restrict__ VTw,
                                                      u16* __restrict__ Ow) {
  __shared__ __align__(16) char smem[65536];   // 2 x (K 16KB + V 16KB)

  const int tid  = threadIdx.x;
  const int lane = tid & 63;
  const int wid  = tid >> 6;
  const int rl   = lane & 31;
  const int hi   = lane >> 5;
  const int blk  = blockIdx.x;
  const int qtr = blk >> 5;
  const int qt  = (blk < 256) ? (15 - qtr) : (qtr - 8);
  const int bh  = blk & 31;
  const int b   = bh >> 4, h = bh & 15, kvh = h >> 1;
  const int q0w = qt * 128 + wid * 32;
  const int qg  = q0w + rl;
  const int kswz = (rl & 15) << 4;     // (32+rl)&15 == rl&15: serves both K reads

  bf16x8 qf[8];
  {
    const u16* qp = Qw + ((size_t)(b * T_) + qg) * (NH * HD) + h * HD + hi * 8;
#pragma unroll
    for (int kd = 0; kd < 8; ++kd) qf[kd] = *reinterpret_cast<const bf16x8*>(qp + kd * 16);
  }

  f32x16 ot[4];
#pragma unroll
  for (int dt = 0; dt < 4; ++dt)
#pragma unroll
    for (int r = 0; r < 16; ++r) ot[dt][r] = 0.f;
  float m = -1e30f, lsum = 0.f;

  auto stageKV = [&](int kt, int p) {
    char* Kb = smem + p * 32768;
    char* Vb = Kb + 16384;
    {
      const int row = tid >> 4, ch = tid & 15;
#pragma unroll
      for (int it = 0; it < 4; ++it) {
        const int rr = it * 16 + row;
        const int scol = ((ch * 16) ^ ((rr & 15) << 4)) >> 1;   // 16-slot swizzle
        gload_lds16(Kw + ((size_t)(b * T_) + kt * 64 + rr) * (NKV * HD) + kvh * HD + scol,
                    Kb + (it * 256 + tid) * 16);
      }
    }
    {
      const int row = tid >> 3, ch = tid & 7;
#pragma unroll
      for (int it = 0; it < 4; ++it) {
        const int rr = it * 32 + row;
        const int scol = ((ch * 16) ^ ((rr & 7) << 4)) >> 1;    // 8-slot (V rows 128B)
        gload_lds16(VTw + ((size_t)((b * NKV + kvh) * HD) + rr) * T_ + kt * 64 + scol,
                    Vb + (it * 256 + tid) * 16);
      }
    }
  };

  const int nkt = 2 * qt + 2;
  stageKV(0, 0);
  __syncthreads();                       // tile 0 landed
  for (int kt = 0; kt < nkt; ++kt) {
    const int cur = kt & 1;
    if (kt + 1 < nkt) stageKV(kt + 1, cur ^ 1);   // in flight under compute

    if (64 * kt <= q0w + 31) {
      const u16* Kb = (const u16*)(smem + cur * 32768);
      const u16* Vb = (const u16*)(smem + cur * 32768 + 16384);

      f32x16 s0, s1;
#pragma unroll
      for (int r = 0; r < 16; ++r) { s0[r] = 0.f; s1[r] = 0.f; }
      __builtin_amdgcn_s_setprio(1);
#pragma unroll
      for (int kd = 0; kd < 8; ++kd) {
        const int cb = (kd * 32 + hi * 16) ^ kswz;
        const bf16x8 k0 = *reinterpret_cast<const bf16x8*>((const char*)Kb + rl * 256 + cb);
        const bf16x8 k1 = *reinterpret_cast<const bf16x8*>((const char*)Kb + (32 + rl) * 256 + cb);
        s0 = __builtin_amdgcn_mfma_f32_32x32x16_bf16(k0, qf[kd], s0, 0, 0, 0);
        s1 = __builtin_amdgcn_mfma_f32_32x32x16_bf16(k1, qf[kd], s1, 0, 0, 0);
      }
      __builtin_amdgcn_s_setprio(0);

      // causal mask + row max (scores already scaled & in base-2 units)
      const int kv0 = kt * 64;
      const bool maskT = (kv0 + 63 > q0w);
      float rm = -1e30f;
      if (maskT) {
#pragma unroll
        for (int r = 0; r < 16; ++r) {
          const int cr = (r & 3) + 8 * (r >> 2) + 4 * hi;
          float a = s0[r], c = s1[r];
          if (kv0 + cr > qg)      a = -1e30f;
          if (kv0 + 32 + cr > qg) c = -1e30f;
          s0[r] = a; s1[r] = c;
          rm = fmaxf(rm, fmaxf(a, c));
        }
      } else {
#pragma unroll
        for (int r = 0; r < 16; ++r) rm = fmaxf(rm, fmaxf(s0[r], s1[r]));
      }
      rm = fmaxf(rm, __shfl_xor(rm, 32));

      // defer-max (single exp path): rescale only if max grew past THR=8
      if (!__all(rm <= m + 8.0f)) {
        const float mn = fmaxf(m, rm);
        const float al = fexp2(m - mn);
        lsum *= al;
#pragma unroll
        for (int dt = 0; dt < 4; ++dt)
#pragma unroll
          for (int r = 0; r < 16; ++r) ot[dt][r] *= al;
        m = mn;
      }
      float rs = 0.f;
#pragma unroll
      for (int r = 0; r < 16; ++r) {
        const float p0 = fexp2(s0[r] - m);
        const float p1 = fexp2(s1[r] - m);
        s0[r] = p0; s1[r] = p1;
        rs += p0 + p1;
      }
      rs += __shfl_xor(rs, 32);
      lsum += rs;

      bf16x8 pf[2][2];
#pragma unroll
      for (int ks = 0; ks < 2; ++ks) {
        {
          uint32_t X0 = cvt_pk_bf16(s0[8 * ks + 0], s0[8 * ks + 1]);
          uint32_t X1 = cvt_pk_bf16(s0[8 * ks + 2], s0[8 * ks + 3]);
          uint32_t Y0 = cvt_pk_bf16(s0[8 * ks + 4], s0[8 * ks + 5]);
          uint32_t Y1 = cvt_pk_bf16(s0[8 * ks + 6], s0[8 * ks + 7]);
          asm volatile("v_permlane32_swap_b32 %0, %1" : "+v"(X0), "+v"(Y0));
          asm volatile("v_permlane32_swap_b32 %0, %1" : "+v"(X1), "+v"(Y1));
          union { uint32_t w[4]; bf16x8 v; } u;
          u.w[0] = X0; u.w[1] = X1; u.w[2] = Y0; u.w[3] = Y1;
          pf[0][ks] = u.v;
        }
        {
          uint32_t X0 = cvt_pk_bf16(s1[8 * ks + 0], s1[8 * ks + 1]);
          uint32_t X1 = cvt_pk_bf16(s1[8 * ks + 2], s1[8 * ks + 3]);
          uint32_t Y0 = cvt_pk_bf16(s1[8 * ks + 4], s1[8 * ks + 5]);
          uint32_t Y1 = cvt_pk_bf16(s1[8 * ks + 6], s1[8 * ks + 7]);
          asm volatile("v_permlane32_swap_b32 %0, %1" : "+v"(X0), "+v"(Y0));
          asm volatile("v_permlane32_swap_b32 %0, %1" : "+v"(X1), "+v"(Y1));
          union { uint32_t w[4]; bf16x8 v; } u;
          u.w[0] = X0; u.w[1] = X1; u.w[2] = Y0; u.w[3] = Y1;
          pf[1][ks] = u.v;
        }
      }

      __builtin_amdgcn_s_setprio(1);
#pragma unroll
      for (int dt = 0; dt < 4; ++dt) {
        const int rv = dt * 32 + rl;
#pragma unroll
        for (int kvc = 0; kvc < 2; ++kvc)
#pragma unroll
          for (int ks = 0; ks < 2; ++ks) {
            const int cb = (kvc * 64 + ks * 32 + hi * 16) ^ ((rv & 7) << 4);
            const bf16x8 vf = *reinterpret_cast<const bf16x8*>((const char*)Vb + rv * 128 + cb);
            ot[dt] = __builtin_amdgcn_mfma_f32_32x32x16_bf16(vf, pf[kvc][ks], ot[dt], 0, 0, 0);
          }
      }
      __builtin_amdgcn_s_setprio(0);
    }
    __syncthreads();                    // drains next-tile staging; frees buf[cur]
  }

  // epilogue: O^T -> LDS transpose -> coalesced global store
  const float inv = 1.0f / lsum;
  u16* ep = (u16*)smem + wid * (32 * 136);
#pragma unroll
  for (int dt = 0; dt < 4; ++dt)
#pragma unroll
    for (int r = 0; r < 16; ++r) {
      const int d = dt * 32 + (r & 3) + 8 * (r >> 2) + 4 * hi;
      ep[rl * 136 + d] = f2bf(ot[dt][r] * inv);
    }
  const int dh = hi * 64;
  const u16* srcp = (u16*)smem + wid * (32 * 136) + rl * 136 + dh;
  u16* gdst = Ow + ((size_t)(b * T_) + q0w + rl) * (NH * HD) + h * HD + dh;
#pragma unroll
  for (int c2 = 0; c2 < 8; ++c2)
    *reinterpret_cast<bf16x8*>(gdst + c2 * 8) =
        *reinterpret_cast<const bf16x8*>(srcp + c2 * 8);
}

// ---------------- host launch ----------------
extern "C" void kernel_launch(void* const* d_in, const int* in_sizes, int n_in,
                              void* d_out, int out_size, void* d_ws, size_t ws_size,
                              hipStream_t stream) {
  (void)in_sizes; (void)n_in; (void)out_size; (void)ws_size;
  const float* x    = (const float*)d_in[0];
  const float* cosT = (const float*)d_in[1];
  const float* sinT = (const float*)d_in[2];
  const int*   pos  = (const int*)d_in[3];
  const float* Wq   = (const float*)d_in[4];
  const float* Wk   = (const float*)d_in[5];
  const float* Wv   = (const float*)d_in[6];
  const float* Wo   = (const float*)d_in[7];
  const float* qw   = (const float*)d_in[8];
  const float* kw   = (const float*)d_in[9];
  float* out = (float*)d_out;

  // workspace map (bytes). Wqb/Wkb/Wvb contiguous -> one [4096][2048] weight.
  char* ws = (char*)d_ws;
  u16* xb   = (u16*)(ws + 0);          // [4096][2048]
  u16* Wqb  = (u16*)(ws + 16777216);   // [2048][2048] (QKV part 1)
  u16* Wob  = (u16*)(ws + 33554432);   // [2048][2048]
  u16* Qws  = (u16*)(ws + 41943040);   // [4096][2048]
  u16* Kws  = (u16*)(ws + 58720256);   // [4096][1024]
  u16* VTws = (u16*)(ws + 67108864);   // [2][1024][2048]
  u16* Aws  = (u16*)(ws + 75497472);   // [4096][2048]

  // one fused conversion launch (regions hard-coded to the ws map above)
  cvt_all<<<20480, 256, 0, stream>>>(x, Wq, Wk, Wv, Wo, (u16*)ws);

  // fused QKV projection: [4096,2048] x [4096,2048]^T, 256 blocks (1/CU)
  gemm2<256, 256, 3><<<256, 512, 0, stream>>>(xb, Wqb, Qws, Kws, VTws,
                                              4096, 4096, 2048);

  rms_rope<<<24576, 256, 0, stream>>>(Qws, Kws, cosT, sinT, pos, qw, kw);

  flash_attn5<<<512, 256, 0, stream>>>(Qws, Kws, VTws, Aws);

  // output projection: [4096,2048] x [2048,2048]^T -> f32, 256 blocks
  gemm2<128, 256, 2><<<256, 512, 0, stream>>>(Aws, Wob, out, nullptr, nullptr,
                                              4096, 2048, 2048);
}